// Round 6
// baseline (170.232 us; speedup 1.0000x reference)
//
#include <hip/hip_runtime.h>
#include <hip/hip_bf16.h>

// x[128][768][28][28] f32 -> per-(b,c) ascending-rank-392 of 784 values,
// then med[128][768] @ W[1000][768]^T + bias -> out[128][1000].

#define NROW 784
#define RANKK 392u
#define NWAVE 4   // rows (waves) per block

// ---------------- Kernel 1: per-wave exact select ----------------------------
// One 64-lane wave per row; no __syncthreads (wave-order LDS semantics).
// Bucket search = 6-probe binary search on the fixed grid T_i=(i-32)/16 using
// wave ballot-counts (v_cmp + s_bcnt) -- ZERO LDS, no atomics, no hist scan.
// Winning interval (~20 elems for this data) is ballot-compacted to LDS
// (16 masked writes + 1 read), then a readlane(SALU) count-rank finisher.
// Exact MSB-radix fallback (LDS atomics) retained for m>64 on arbitrary data.
__global__ __launch_bounds__(256) void kth_select_kernel(
    const float* __restrict__ x, float* __restrict__ med) {
  __shared__ float cand[NWAVE][NROW];      // 12544 B
  __shared__ unsigned hist[NWAVE][64];     // 1024 B (fallback only)

  const int tid  = threadIdx.x;
  const int lane = tid & 63;
  const int w    = tid >> 6;
  const int row  = blockIdx.x * NWAVE + w;
  const float4* src4 = (const float4*)(x + (size_t)row * NROW);
  const unsigned long long ltm = (1ull << lane) - 1ull;

  // ---- load row: 196 float4 spread as {lane, 64+lane, 128+lane, 192+lane<4}
  float4 f0 = src4[lane];
  float4 f1 = src4[64 + lane];
  float4 f2 = src4[128 + lane];
  const bool v3 = (lane < 4);
  float4 f3 = make_float4(0.f, 0.f, 0.f, 0.f);
  if (v3) f3 = src4[192 + lane];

  // invalid tail slots get +INF so they never count as "< t"
  const float inf = __int_as_float(0x7f800000);
  float vv[16] = {f0.x, f0.y, f0.z, f0.w, f1.x, f1.y, f1.z, f1.w,
                  f2.x, f2.y, f2.z, f2.w,
                  v3 ? f3.x : inf, v3 ? f3.y : inf,
                  v3 ? f3.z : inf, v3 ? f3.w : inf};

  // ---- binary search for bucket D: c(T_D) <= r < c(T_{D+1}),
  //      T_i = (i-32)/16, virtual c(T_0)=0, c(T_64)=784 (clamp buckets).
  unsigned r = RANKK;
  int lo = 0, hi = 64;
  unsigned clo = 0u, chi = NROW;
#pragma unroll
  for (int it = 0; it < 6; ++it) {
    const int mid = (lo + hi) >> 1;
    const float t = (float)(mid - 32) * 0.0625f;
    unsigned c = 0;
#pragma unroll
    for (int j = 0; j < 16; ++j)
      c += (unsigned)__popcll(__ballot(vv[j] < t));
    if (c <= r) { lo = mid; clo = c; } else { hi = mid; chi = c; }
  }
  unsigned m = chi - clo;
  r -= clo;

  // ---- ballot-compact winning-interval values into cand[w][0..m-1]
  {
    const float tLo = (float)(lo - 32) * 0.0625f;
    const float tHi = (float)(hi - 32) * 0.0625f;
    const bool openLo = (lo == 0);
    const bool openHi = (hi == 64);
    unsigned base = 0;
#pragma unroll
    for (int j = 0; j < 16; ++j) {
      const bool va = (j < 12) || v3;
      const bool match = va && (openLo || vv[j] >= tLo) &&
                               (openHi || vv[j] < tHi);
      const unsigned long long mk = __ballot(match);
      if (match) cand[w][base + (unsigned)__popcll(mk & ltm)] = vv[j];
      base += (unsigned)__popcll(mk);    // uniform -> SALU
    }
  }

  // ---- fallback: exact MSB 6-bit radix refinement (only if m > 64)
#pragma unroll 1
  for (int p = 0; p < 6; ++p) {
    if (m <= 64u) break;
    const int shift = (p < 5) ? (26 - 6 * p) : 0;
    hist[w][lane] = 0u;
    const int nch = (int)((m + 63u) >> 6);
    for (int c = 0; c < nch; ++c) {
      const int idx = (c << 6) + lane;
      if (idx < (int)m) {
        const unsigned b = __float_as_uint(cand[w][idx]);
        const unsigned key = (b & 0x80000000u) ? ~b : (b | 0x80000000u);
        atomicAdd(&hist[w][(key >> shift) & 63u], 1u);
      }
    }
    const unsigned cnt = hist[w][lane];
    unsigned incl = cnt;
#pragma unroll
    for (int off = 1; off < 64; off <<= 1) {
      unsigned t = __shfl_up(incl, off, 64);
      if (lane >= off) incl += t;
    }
    const unsigned excl = incl - cnt;
    const bool hit = (r >= excl) && (r < incl);
    const unsigned long long hm = __ballot(hit);
    const int Dp = __ffsll(hm) - 1;
    r -= __shfl(excl, Dp, 64);
    const unsigned m2 = __shfl(cnt, Dp, 64);
    // in-place ballot compact: each chunk fully read (one wave-wide ds_read)
    // before its writes; cumulative write index <= read index -> safe.
    unsigned base = 0;
    for (int c = 0; c < nch; ++c) {
      const int idx = (c << 6) + lane;
      const bool va = idx < (int)m;
      const float f = va ? cand[w][idx] : 0.f;
      const unsigned b = __float_as_uint(f);
      const unsigned key = (b & 0x80000000u) ? ~b : (b | 0x80000000u);
      const bool match = va && (((key >> shift) & 63u) == (unsigned)Dp);
      const unsigned long long mk = __ballot(match);
      if (match) cand[w][base + (unsigned)__popcll(mk & ltm)] = f;
      base += (unsigned)__popcll(mk);
    }
    m = m2;
  }

  // ---- finisher: one LDS read, then readlane(SALU)-broadcast count loop
  float sel = 0.f;
  bool win = false;
  if (m > 64u) {
    // exhausted all key bits -> remaining candidates identical
    sel = cand[w][0];
    win = (lane == 0);
  } else {
    const float myv = cand[w][lane];       // lanes >= m hold garbage; masked below
    unsigned cl = 0, ce = 0;
    for (int j = 0; j < (int)m; ++j) {     // j uniform -> readlane is SALU
      const float kj =
          __int_as_float(__builtin_amdgcn_readlane(__float_as_int(myv), j));
      cl += (kj < myv) ? 1u : 0u;
      ce += (kj == myv) ? 1u : 0u;
    }
    sel = myv;
    win = (lane < (int)m) && (cl <= r) && (r < cl + ce);
  }
  if (win) med[row] = sel;                 // duplicates write the same value
}

// ---------------- Kernel 2: small f32 GEMM out = med @ W^T + bias ------------
#define GO 32
#define GB 16
#define GK 64

__global__ __launch_bounds__(256) void gemm_kernel(
    const float* __restrict__ med, const float* __restrict__ W,
    const float* __restrict__ bias, float* __restrict__ out) {
  __shared__ float Ws[GK][GO + 1];  // [kc][ol], stride 33 -> conflict-free
  __shared__ float Ms[GB][GK];

  const int o0 = blockIdx.x * GO;
  const int b0 = blockIdx.y * GB;
  const int tid = threadIdx.x;
  const int to = tid & 31;
  const int tb = tid >> 5;   // 0..7, two b's each

  float acc0 = 0.f, acc1 = 0.f;

  for (int k0 = 0; k0 < 768; k0 += GK) {
#pragma unroll
    for (int idx = tid; idx < GO * GK; idx += 256) {
      const int kc = idx & (GK - 1);
      const int ol = idx >> 6;
      const int o = o0 + ol;
      Ws[kc][ol] = (o < 1000) ? W[(size_t)o * 768 + k0 + kc] : 0.f;
    }
#pragma unroll
    for (int idx = tid; idx < GB * GK; idx += 256) {
      const int kc = idx & (GK - 1);
      const int bl = idx >> 6;
      Ms[bl][kc] = med[(size_t)(b0 + bl) * 768 + k0 + kc];
    }
    __syncthreads();

    const int bl = tb * 2;
#pragma unroll
    for (int kk = 0; kk < GK; ++kk) {
      const float wv = Ws[kk][to];
      acc0 = fmaf(Ms[bl][kk], wv, acc0);
      acc1 = fmaf(Ms[bl + 1][kk], wv, acc1);
    }
    __syncthreads();
  }

  const int o = o0 + to;
  if (o < 1000) {
    const float bb = bias[o];
    const int b = b0 + tb * 2;
    out[(size_t)b * 1000 + o] = acc0 + bb;
    out[(size_t)(b + 1) * 1000 + o] = acc1 + bb;
  }
}

extern "C" void kernel_launch(void* const* d_in, const int* in_sizes, int n_in,
                              void* d_out, int out_size, void* d_ws, size_t ws_size,
                              hipStream_t stream) {
  const float* x = (const float*)d_in[0];    // [128,768,28,28]
  const float* W = (const float*)d_in[1];    // [1000,768]
  const float* b = (const float*)d_in[2];    // [1000]
  float* out = (float*)d_out;                // [128,1000]
  float* med = (float*)d_ws;                 // [128,768] scratch

  const int rows = 128 * 768;                // 98304
  kth_select_kernel<<<rows / NWAVE, 256, 0, stream>>>(x, med);

  dim3 grid((1000 + GO - 1) / GO, 128 / GB); // (32, 8)
  gemm_kernel<<<grid, 256, 0, stream>>>(med, W, b, out);
}

// Round 7
// 146.796 us; speedup vs baseline: 1.1597x; 1.1597x over previous
//
#include <hip/hip_runtime.h>
#include <hip/hip_bf16.h>

// x[128][768][28][28] f32 -> per-(b,c) ascending-rank-392 of 784 values,
// then med[128][768] @ W[1000][768]^T + bias -> out[128][1000].

#define NROW 784
#define RANKK 392u
#define NWAVE 4   // rows (waves) per block

// ---------------- Kernel 1: per-wave exact select ----------------------------
// One 64-lane wave per row; no __syncthreads (wave-order LDS semantics).
// Main path (pipe-budgeted: ~17 DS, ~350 VALU, ~60 SALU per row):
//   1. ONE per-lane VALU pass counts v<t for 5 fixed thresholds
//      {-.125,-.0625,0,.0625,.125} (no LDS, no atomics, no ballots).
//   2. Counts packed 10-bit into 2 u32s -> one butterfly reduce (12 shfl).
//   3. Winning 1/16-wide interval picked scalar-ly (m ~= 20 for N(0,1));
//      ballot-compact it to LDS (<=16 masked writes, empties skipped).
//   4. readlane(VALU) count-rank finisher, no DS in loop.
// Fallback (~0.5% of rows + any adversarial data): r3-proven scale-16
// histogram + MSB-radix refinement, exact for arbitrary input.
__global__ __launch_bounds__(256) void kth_select_kernel(
    const float* __restrict__ x, float* __restrict__ med) {
  __shared__ float cand[NWAVE][NROW];      // 12544 B
  __shared__ unsigned hist[NWAVE][4][65];  // 4160 B (fallback only)

  const int tid  = threadIdx.x;
  const int lane = tid & 63;
  const int w    = tid >> 6;
  const int row  = blockIdx.x * NWAVE + w;
  const float4* src4 = (const float4*)(x + (size_t)row * NROW);
  const unsigned long long ltm = (1ull << lane) - 1ull;
  const int sub = lane & 3;

  // ---- load row: 196 float4 spread as {lane, 64+lane, 128+lane, 192+lane<4}
  float4 f0 = src4[lane];
  float4 f1 = src4[64 + lane];
  float4 f2 = src4[128 + lane];
  const bool v3 = (lane < 4);
  float4 f3 = make_float4(0.f, 0.f, 0.f, 0.f);
  if (v3) f3 = src4[192 + lane];

  // invalid tail slots get +INF: never counted, never match an interval
  const float inf = __int_as_float(0x7f800000);
  const float vv[16] = {f0.x, f0.y, f0.z, f0.w, f1.x, f1.y, f1.z, f1.w,
                        f2.x, f2.y, f2.z, f2.w,
                        v3 ? f3.x : inf, v3 ? f3.y : inf,
                        v3 ? f3.z : inf, v3 ? f3.w : inf};

  // ---- 1. per-lane counts at 5 thresholds (pure VALU: v_cmp + addc)
  unsigned c0 = 0, c1 = 0, c2 = 0, c3 = 0, c4 = 0;
#pragma unroll
  for (int j = 0; j < 16; ++j) {
    const float v = vv[j];
    c0 += (v < -0.125f);
    c1 += (v < -0.0625f);
    c2 += (v <  0.0f);
    c3 += (v <  0.0625f);
    c4 += (v <  0.125f);
  }

  // ---- 2. pack (counts <= 784 < 1024 per 10-bit field) + butterfly reduce
  unsigned pA = (c0 << 20) | (c1 << 10) | c2;
  unsigned pB = (c3 << 10) | c4;
#pragma unroll
  for (int off = 1; off < 64; off <<= 1) {
    pA += __shfl_xor(pA, off, 64);
    pB += __shfl_xor(pB, off, 64);
  }
  const unsigned C1 = pA >> 20, C2 = (pA >> 10) & 1023u, C3 = pA & 1023u;
  const unsigned C4 = pB >> 10, C5 = pB & 1023u;

  // ---- 3. pick interval containing rank; fast iff finite-bounded and m<=64
  unsigned r = RANKK;
  unsigned m = 0;
  float tLo = 0.f, tHi = 0.f;
  bool fast = false;
  if (C1 <= RANKK && RANKK < C5) {
    unsigned cl, ch;
    int ti;
    if (RANKK < C2)      { ti = 0; cl = C1; ch = C2; }
    else if (RANKK < C3) { ti = 1; cl = C2; ch = C3; }
    else if (RANKK < C4) { ti = 2; cl = C3; ch = C4; }
    else                 { ti = 3; cl = C4; ch = C5; }
    m = ch - cl;
    if (m <= 64u) {
      fast = true;
      r = RANKK - cl;
      tLo = -0.125f + 0.0625f * (float)ti;
      tHi = tLo + 0.0625f;
    }
  }

  if (fast) {
    // ---- ballot-compact winning interval into cand[w][0..m-1]
    unsigned base = 0;
#pragma unroll
    for (int j = 0; j < 16; ++j) {
      const bool match = (vv[j] >= tLo) && (vv[j] < tHi);
      const unsigned long long mk = __ballot(match);
      if (match) cand[w][base + (unsigned)__popcll(mk & ltm)] = vv[j];
      base += (unsigned)__popcll(mk);    // uniform -> SALU
    }
  } else {
    // ================= fallback: exact histogram + radix (r3-proven) ========
    m = 0;
    r = RANKK;
#pragma unroll
    for (int s = 0; s < 4; ++s) hist[w][s][lane] = 0u;
#pragma unroll
    for (int j = 0; j < 16; ++j) {
      const bool va = (j < 12) || v3;
      if (va) {
        int bi = __float2int_rd(fmaf(vv[j], 16.f, 32.f));
        bi = min(max(bi, 0), 63);
        atomicAdd(&hist[w][sub][bi], 1u);
      }
    }
    int D;
    {
      const unsigned cnt = hist[w][0][lane] + hist[w][1][lane] +
                           hist[w][2][lane] + hist[w][3][lane];
      unsigned incl = cnt;
#pragma unroll
      for (int off = 1; off < 64; off <<= 1) {
        unsigned t = __shfl_up(incl, off, 64);
        if (lane >= off) incl += t;
      }
      const unsigned excl = incl - cnt;
      const bool hit = (r >= excl) && (r < incl);
      const unsigned long long hm = __ballot(hit);
      D = __ffsll(hm) - 1;
      r -= __shfl(excl, D, 64);
      m  = __shfl(cnt,  D, 64);
    }
    {
      unsigned base = 0;
#pragma unroll
      for (int j = 0; j < 16; ++j) {
        const bool va = (j < 12) || v3;
        int bi = __float2int_rd(fmaf(vv[j], 16.f, 32.f));
        bi = min(max(bi, 0), 63);
        const bool match = va && (bi == D);
        const unsigned long long mk = __ballot(match);
        if (match) cand[w][base + (unsigned)__popcll(mk & ltm)] = vv[j];
        base += (unsigned)__popcll(mk);
      }
    }
    // exact MSB 6-bit radix refinement while m > 64
#pragma unroll 1
    for (int p = 0; p < 6; ++p) {
      if (m <= 64u) break;
      const int shift = (p < 5) ? (26 - 6 * p) : 0;
      hist[w][0][lane] = 0u;
      const int nch = (int)((m + 63u) >> 6);
      for (int c = 0; c < nch; ++c) {
        const int idx = (c << 6) + lane;
        if (idx < (int)m) {
          const unsigned b = __float_as_uint(cand[w][idx]);
          const unsigned key = (b & 0x80000000u) ? ~b : (b | 0x80000000u);
          atomicAdd(&hist[w][0][(key >> shift) & 63u], 1u);
        }
      }
      const unsigned cnt = hist[w][0][lane];
      unsigned incl = cnt;
#pragma unroll
      for (int off = 1; off < 64; off <<= 1) {
        unsigned t = __shfl_up(incl, off, 64);
        if (lane >= off) incl += t;
      }
      const unsigned excl = incl - cnt;
      const bool hit = (r >= excl) && (r < incl);
      const unsigned long long hm = __ballot(hit);
      const int Dp = __ffsll(hm) - 1;
      r -= __shfl(excl, Dp, 64);
      const unsigned m2 = __shfl(cnt, Dp, 64);
      // in-place ballot compact: each chunk fully read (one wave-wide read)
      // before its writes; cumulative write index <= read index -> safe.
      unsigned base = 0;
      for (int c = 0; c < nch; ++c) {
        const int idx = (c << 6) + lane;
        const bool va = idx < (int)m;
        const float f = va ? cand[w][idx] : 0.f;
        const unsigned b = __float_as_uint(f);
        const unsigned key = (b & 0x80000000u) ? ~b : (b | 0x80000000u);
        const bool match = va && (((key >> shift) & 63u) == (unsigned)Dp);
        const unsigned long long mk = __ballot(match);
        if (match) cand[w][base + (unsigned)__popcll(mk & ltm)] = f;
        base += (unsigned)__popcll(mk);
      }
      m = m2;
    }
  }

  // ---- 4. finisher: one LDS read + readlane(VALU) count-rank loop
  float sel = 0.f;
  bool win = false;
  if (m > 64u) {
    // radix exhausted all key bits -> remaining candidates identical
    sel = cand[w][0];
    win = (lane == 0);
  } else {
    const float myv = cand[w][lane];       // lanes >= m: garbage, masked below
    unsigned cl = 0, ce = 0;
    for (int j = 0; j < (int)m; ++j) {     // j uniform
      const float kj =
          __int_as_float(__builtin_amdgcn_readlane(__float_as_int(myv), j));
      cl += (kj < myv) ? 1u : 0u;
      ce += (kj == myv) ? 1u : 0u;
    }
    sel = myv;
    win = (lane < (int)m) && (cl <= r) && (r < cl + ce);
  }
  if (win) med[row] = sel;                 // duplicates write the same value
}

// ---------------- Kernel 2: small f32 GEMM out = med @ W^T + bias ------------
#define GO 32
#define GB 16
#define GK 64

__global__ __launch_bounds__(256) void gemm_kernel(
    const float* __restrict__ med, const float* __restrict__ W,
    const float* __restrict__ bias, float* __restrict__ out) {
  __shared__ float Ws[GK][GO + 1];  // [kc][ol], stride 33 -> conflict-free
  __shared__ float Ms[GB][GK];

  const int o0 = blockIdx.x * GO;
  const int b0 = blockIdx.y * GB;
  const int tid = threadIdx.x;
  const int to = tid & 31;
  const int tb = tid >> 5;   // 0..7, two b's each

  float acc0 = 0.f, acc1 = 0.f;

  for (int k0 = 0; k0 < 768; k0 += GK) {
#pragma unroll
    for (int idx = tid; idx < GO * GK; idx += 256) {
      const int kc = idx & (GK - 1);
      const int ol = idx >> 6;
      const int o = o0 + ol;
      Ws[kc][ol] = (o < 1000) ? W[(size_t)o * 768 + k0 + kc] : 0.f;
    }
#pragma unroll
    for (int idx = tid; idx < GB * GK; idx += 256) {
      const int kc = idx & (GK - 1);
      const int bl = idx >> 6;
      Ms[bl][kc] = med[(size_t)(b0 + bl) * 768 + k0 + kc];
    }
    __syncthreads();

    const int bl = tb * 2;
#pragma unroll
    for (int kk = 0; kk < GK; ++kk) {
      const float wv = Ws[kk][to];
      acc0 = fmaf(Ms[bl][kk], wv, acc0);
      acc1 = fmaf(Ms[bl + 1][kk], wv, acc1);
    }
    __syncthreads();
  }

  const int o = o0 + to;
  if (o < 1000) {
    const float bb = bias[o];
    const int b = b0 + tb * 2;
    out[(size_t)b * 1000 + o] = acc0 + bb;
    out[(size_t)(b + 1) * 1000 + o] = acc1 + bb;
  }
}

extern "C" void kernel_launch(void* const* d_in, const int* in_sizes, int n_in,
                              void* d_out, int out_size, void* d_ws, size_t ws_size,
                              hipStream_t stream) {
  const float* x = (const float*)d_in[0];    // [128,768,28,28]
  const float* W = (const float*)d_in[1];    // [1000,768]
  const float* b = (const float*)d_in[2];    // [1000]
  float* out = (float*)d_out;                // [128,1000]
  float* med = (float*)d_ws;                 // [128,768] scratch

  const int rows = 128 * 768;                // 98304
  kth_select_kernel<<<rows / NWAVE, 256, 0, stream>>>(x, med);

  dim3 grid((1000 + GO - 1) / GO, 128 / GB); // (32, 8)
  gemm_kernel<<<grid, 256, 0, stream>>>(med, W, b, out);
}

// Round 8
// 141.106 us; speedup vs baseline: 1.2064x; 1.0403x over previous
//
#include <hip/hip_runtime.h>
#include <hip/hip_bf16.h>

// x[128][768][28][28] f32 -> per-(b,c) ascending-rank-392 of 784 values,
// then med[128][768] @ W[1000][768]^T + bias -> out[128][1000].

#define NROW 784
#define RANKK 392
#define NWAVE 4   // rows (waves) per block

// ---------------- Kernel 1: per-wave exact select ----------------------------
// One 64-lane wave per row; no __syncthreads (wave-order LDS semantics).
// KEY FIX vs r5-r7: every control value (counts, interval pick, m, r) is
// forced into SGPRs via readfirstlane, so all loops are scalar-bounded and
// all branches wave-uniform -- no divergent-loop / waterfall codegen.
// Pipeline: 5-threshold VALU count pass -> 1 butterfly reduce (2 packed words)
// -> scalar interval pick (grid -0.2,-0.1,0,0.1,0.2) -> ballot+mbcnt compact
// (~16 DS writes) -> float4-broadcast finisher (4 candidates per DS op).
// Fallback for rank outside (-0.2,0.2) or m>64: r3/r4-proven exact histogram
// + MSB-radix refinement (any data distribution).
__global__ __launch_bounds__(256) void kth_select_kernel(
    const float* __restrict__ x, float* __restrict__ med) {
  __shared__ __align__(16) float cand[NWAVE][NROW];   // 12544 B
  __shared__ unsigned hist[NWAVE][4][65];             // 4160 B (fallback only)

  const int tid  = threadIdx.x;
  const int lane = tid & 63;
  const int w    = tid >> 6;
  const int row  = blockIdx.x * NWAVE + w;
  const float4* src4 = (const float4*)(x + (size_t)row * NROW);
  const int sub = lane & 3;
  const float inf = __int_as_float(0x7f800000);

  // ---- load row: 196 float4 spread as {lane, 64+lane, 128+lane, 192+lane<4}
  float4 f0 = src4[lane];
  float4 f1 = src4[64 + lane];
  float4 f2 = src4[128 + lane];
  const bool v3 = (lane < 4);
  float4 f3 = make_float4(inf, inf, inf, inf);   // +INF: inert in counts/compare
  if (v3) f3 = src4[192 + lane];

  const float vv[16] = {f0.x, f0.y, f0.z, f0.w, f1.x, f1.y, f1.z, f1.w,
                        f2.x, f2.y, f2.z, f2.w, f3.x, f3.y, f3.z, f3.w};

  // ---- per-lane counts at 5 fixed thresholds (pure VALU)
  unsigned c0 = 0, c1 = 0, c2 = 0, c3 = 0, c4 = 0;
#pragma unroll
  for (int j = 0; j < 16; ++j) {
    const float v = vv[j];
    c0 += (v < -0.2f);
    c1 += (v < -0.1f);
    c2 += (v <  0.0f);
    c3 += (v <  0.1f);
    c4 += (v <  0.2f);
  }

  // ---- one butterfly reduce over 2 packed words (fields <= 784 < 1024)
  unsigned pA = (c0 << 20) | (c1 << 10) | c2;
  unsigned pB = (c3 << 10) | c4;
#pragma unroll
  for (int off = 1; off < 64; off <<= 1) {
    pA += __shfl_xor(pA, off, 64);
    pB += __shfl_xor(pB, off, 64);
  }
  // force scalar: downstream control must be SGPR-resident
  const unsigned sA = __builtin_amdgcn_readfirstlane(pA);
  const unsigned sB = __builtin_amdgcn_readfirstlane(pB);
  const int b0 = sA >> 20, b1 = (sA >> 10) & 1023, b2 = sA & 1023;
  const int b3 = sB >> 10, b4 = sB & 1023;

  int ms = 0, r2 = 0;
  bool done = false;
  bool fastok = (b0 <= RANKK) && (RANKK < b4);
  if (fastok) {
    float tA, tB;
    int blo, bhi;
    if (RANKK < b1)      { tA = -0.2f; tB = -0.1f; blo = b0; bhi = b1; }
    else if (RANKK < b2) { tA = -0.1f; tB =  0.0f; blo = b1; bhi = b2; }
    else if (RANKK < b3) { tA =  0.0f; tB =  0.1f; blo = b2; bhi = b3; }
    else                 { tA =  0.1f; tB =  0.2f; blo = b3; bhi = b4; }
    ms = bhi - blo;
    r2 = RANKK - blo;
    if (ms <= 64) {
      // ---- ballot + mbcnt compact winning interval into cand[w][0..ms-1]
      unsigned base = 0;
#pragma unroll
      for (int j = 0; j < 16; ++j) {
        const bool match = (vv[j] >= tA) && (vv[j] < tB);
        const unsigned long long mk = __ballot(match);
        if (match) {
          const unsigned pos = __builtin_amdgcn_mbcnt_hi(
              (unsigned)(mk >> 32),
              __builtin_amdgcn_mbcnt_lo((unsigned)mk, 0u));
          cand[w][base + pos] = vv[j];
        }
        base += (unsigned)__popcll(mk);   // uniform -> SALU
      }
    } else {
      fastok = false;
    }
  }

  if (!fastok) {
    // ================= fallback: exact histogram + radix (r3-proven) ========
    const unsigned long long ltm = (1ull << lane) - 1ull;
    unsigned r = RANKK;
    unsigned m = 0;
#pragma unroll
    for (int s = 0; s < 4; ++s) hist[w][s][lane] = 0u;
#pragma unroll
    for (int j = 0; j < 16; ++j) {
      if (vv[j] != inf || ((j < 12) || v3)) {   // INF tails excluded below anyway
        int bi = __float2int_rd(fmaf(vv[j], 16.f, 32.f));
        bi = min(max(bi, 0), 63);
        if ((j < 12) || v3) atomicAdd(&hist[w][sub][bi], 1u);
      }
    }
    int D;
    {
      const unsigned cnt = hist[w][0][lane] + hist[w][1][lane] +
                           hist[w][2][lane] + hist[w][3][lane];
      unsigned incl = cnt;
#pragma unroll
      for (int off = 1; off < 64; off <<= 1) {
        unsigned t = __shfl_up(incl, off, 64);
        if (lane >= off) incl += t;
      }
      const unsigned excl = incl - cnt;
      const bool hit = (r >= excl) && (r < incl);
      const unsigned long long hm = __ballot(hit);
      D = __ffsll(hm) - 1;
      r -= __shfl(excl, D, 64);
      m  = __shfl(cnt,  D, 64);
    }
    {
      unsigned base = 0;
#pragma unroll
      for (int j = 0; j < 16; ++j) {
        const bool va = (j < 12) || v3;
        int bi = __float2int_rd(fmaf(vv[j], 16.f, 32.f));
        bi = min(max(bi, 0), 63);
        const bool match = va && (bi == D);
        const unsigned long long mk = __ballot(match);
        if (match) cand[w][base + (unsigned)__popcll(mk & ltm)] = vv[j];
        base += (unsigned)__popcll(mk);
      }
    }
    // exact MSB 6-bit radix refinement while m > 64
#pragma unroll 1
    for (int p = 0; p < 6; ++p) {
      if (m <= 64u) break;
      const int shift = (p < 5) ? (26 - 6 * p) : 0;
      hist[w][0][lane] = 0u;
      const int nch = (int)((m + 63u) >> 6);
      for (int c = 0; c < nch; ++c) {
        const int idx = (c << 6) + lane;
        if (idx < (int)m) {
          const unsigned b = __float_as_uint(cand[w][idx]);
          const unsigned key = (b & 0x80000000u) ? ~b : (b | 0x80000000u);
          atomicAdd(&hist[w][0][(key >> shift) & 63u], 1u);
        }
      }
      const unsigned cnt = hist[w][0][lane];
      unsigned incl = cnt;
#pragma unroll
      for (int off = 1; off < 64; off <<= 1) {
        unsigned t = __shfl_up(incl, off, 64);
        if (lane >= off) incl += t;
      }
      const unsigned excl = incl - cnt;
      const bool hit = (r >= excl) && (r < incl);
      const unsigned long long hm = __ballot(hit);
      const int Dp = __ffsll(hm) - 1;
      r -= __shfl(excl, Dp, 64);
      const unsigned m2 = __shfl(cnt, Dp, 64);
      // in-place ballot compact: each chunk fully read before its writes;
      // cumulative write index <= read index -> safe.
      unsigned base = 0;
      for (int c = 0; c < nch; ++c) {
        const int idx = (c << 6) + lane;
        const bool va = idx < (int)m;
        const float f = va ? cand[w][idx] : 0.f;
        const unsigned b = __float_as_uint(f);
        const unsigned key = (b & 0x80000000u) ? ~b : (b | 0x80000000u);
        const bool match = va && (((key >> shift) & 63u) == (unsigned)Dp);
        const unsigned long long mk = __ballot(match);
        if (match) cand[w][base + (unsigned)__popcll(mk & ltm)] = f;
        base += (unsigned)__popcll(mk);
      }
      m = m2;
    }
    if (m > 64u) {
      // radix exhausted all key bits -> remaining candidates identical
      if (lane == 0) med[row] = cand[w][0];
      done = true;
    } else {
      ms = __builtin_amdgcn_readfirstlane((int)m);   // scalarize control
      r2 = __builtin_amdgcn_readfirstlane((int)r);
    }
  }

  // ---- shared finisher: float4 LDS broadcasts, scalar loop bound -----------
  if (!done) {
    if (lane < 4) cand[w][ms + lane] = inf;   // pad to x4 (ms+4 <= 68 < 784)
    const float myv = cand[w][lane];          // lanes >= ms: garbage, masked
    unsigned cl = 0, ce = 0;
    const int nq = (ms + 3) >> 2;
    for (int q = 0; q < nq; ++q) {            // scalar loop, ds_read_b128 bcast
      const float4 cq = *((const float4*)&cand[w][q << 2]);
      cl += (cq.x < myv) + (cq.y < myv) + (cq.z < myv) + (cq.w < myv);
      ce += (cq.x == myv) + (cq.y == myv) + (cq.z == myv) + (cq.w == myv);
    }
    if ((lane < ms) && (cl <= (unsigned)r2) && ((unsigned)r2 < cl + ce))
      med[row] = myv;                         // duplicates write same value
  }
}

// ---------------- Kernel 2: small f32 GEMM out = med @ W^T + bias ------------
#define GO 32
#define GB 16
#define GK 64

__global__ __launch_bounds__(256) void gemm_kernel(
    const float* __restrict__ med, const float* __restrict__ W,
    const float* __restrict__ bias, float* __restrict__ out) {
  __shared__ float Ws[GK][GO + 1];  // [kc][ol], stride 33 -> conflict-free
  __shared__ float Ms[GB][GK];

  const int o0 = blockIdx.x * GO;
  const int b0 = blockIdx.y * GB;
  const int tid = threadIdx.x;
  const int to = tid & 31;
  const int tb = tid >> 5;   // 0..7, two b's each

  float acc0 = 0.f, acc1 = 0.f;

  for (int k0 = 0; k0 < 768; k0 += GK) {
#pragma unroll
    for (int idx = tid; idx < GO * GK; idx += 256) {
      const int kc = idx & (GK - 1);
      const int ol = idx >> 6;
      const int o = o0 + ol;
      Ws[kc][ol] = (o < 1000) ? W[(size_t)o * 768 + k0 + kc] : 0.f;
    }
#pragma unroll
    for (int idx = tid; idx < GB * GK; idx += 256) {
      const int kc = idx & (GK - 1);
      const int bl = idx >> 6;
      Ms[bl][kc] = med[(size_t)(b0 + bl) * 768 + k0 + kc];
    }
    __syncthreads();

    const int bl = tb * 2;
#pragma unroll
    for (int kk = 0; kk < GK; ++kk) {
      const float wv = Ws[kk][to];
      acc0 = fmaf(Ms[bl][kk], wv, acc0);
      acc1 = fmaf(Ms[bl + 1][kk], wv, acc1);
    }
    __syncthreads();
  }

  const int o = o0 + to;
  if (o < 1000) {
    const float bb = bias[o];
    const int b = b0 + tb * 2;
    out[(size_t)b * 1000 + o] = acc0 + bb;
    out[(size_t)(b + 1) * 1000 + o] = acc1 + bb;
  }
}

extern "C" void kernel_launch(void* const* d_in, const int* in_sizes, int n_in,
                              void* d_out, int out_size, void* d_ws, size_t ws_size,
                              hipStream_t stream) {
  const float* x = (const float*)d_in[0];    // [128,768,28,28]
  const float* W = (const float*)d_in[1];    // [1000,768]
  const float* b = (const float*)d_in[2];    // [1000]
  float* out = (float*)d_out;                // [128,1000]
  float* med = (float*)d_ws;                 // [128,768] scratch

  const int rows = 128 * 768;                // 98304
  kth_select_kernel<<<rows / NWAVE, 256, 0, stream>>>(x, med);

  dim3 grid((1000 + GO - 1) / GO, 128 / GB); // (32, 8)
  gemm_kernel<<<grid, 256, 0, stream>>>(med, W, b, out);
}

// Round 9
// 76.368 us; speedup vs baseline: 2.2291x; 1.8477x over previous
//
#include <hip/hip_runtime.h>
#include <hip/hip_bf16.h>

// x[128][768][28][28] f32 -> per-(b,c) ascending-rank-392 of 784 values,
// then med[128][768] @ W[1000][768]^T + bias -> out[128][1000].

#define NROW 784
#define RANKK 392u
#define NWAVE 4   // rows (waves) per block

// ---------------- Kernel 1: per-wave exact select (r4 verbatim, best) --------
__global__ __launch_bounds__(256) void kth_select_kernel(
    const float* __restrict__ x, float* __restrict__ med) {
  __shared__ unsigned cand[NWAVE][NROW];     // 12544 B
  __shared__ unsigned hist[NWAVE][4][65];    // 4160 B (stride 65 staggers banks)
  __shared__ unsigned apcnt[NWAVE];

  const int tid  = threadIdx.x;
  const int lane = tid & 63;
  const int w    = tid >> 6;
  const int row  = blockIdx.x * NWAVE + w;
  const float4* src4 = (const float4*)(x + (size_t)row * NROW);
  const int sub = lane & 3;

  float4 f0 = src4[lane];
  float4 f1 = src4[64 + lane];
  float4 f2 = src4[128 + lane];
  const bool v3 = (lane < 4);
  float4 f3 = make_float4(0.f, 0.f, 0.f, 0.f);
  if (v3) f3 = src4[192 + lane];

  const float vv[16] = {f0.x, f0.y, f0.z, f0.w, f1.x, f1.y, f1.z, f1.w,
                        f2.x, f2.y, f2.z, f2.w, f3.x, f3.y, f3.z, f3.w};

  int bkt[16];
#pragma unroll
  for (int j = 0; j < 16; ++j) {
    const int bi = __float2int_rd(fmaf(vv[j], 32.f, 32.f));
    bkt[j] = min(max(bi, 0), 63);
  }

#pragma unroll
  for (int s = 0; s < 4; ++s) hist[w][s][lane] = 0u;
  if (lane == 0) apcnt[w] = 0u;
#pragma unroll
  for (int j = 0; j < 12; ++j) atomicAdd(&hist[w][sub][bkt[j]], 1u);
  if (v3) {
#pragma unroll
    for (int j = 12; j < 16; ++j) atomicAdd(&hist[w][sub][bkt[j]], 1u);
  }

  unsigned r = RANKK;
  unsigned m;
  int D;
  {
    unsigned cnt = hist[w][0][lane] + hist[w][1][lane] + hist[w][2][lane] + hist[w][3][lane];
    unsigned incl = cnt;
#pragma unroll
    for (int off = 1; off < 64; off <<= 1) {
      unsigned t = __shfl_up(incl, off, 64);
      if (lane >= off) incl += t;
    }
    const unsigned excl = incl - cnt;
    const bool hit = (r >= excl) && (r < incl);
    const unsigned long long hm = __ballot(hit);
    D = __ffsll(hm) - 1;
    r -= __shfl(excl, D, 64);
    m  = __shfl(cnt,  D, 64);
  }

#pragma unroll
  for (int j = 0; j < 16; ++j) {
    const bool va = (j < 12) || v3;
    if (va && bkt[j] == D) {
      const unsigned b = __float_as_uint(vv[j]);
      const unsigned key = (b & 0x80000000u) ? ~b : (b | 0x80000000u);
      const unsigned slot = atomicAdd(&apcnt[w], 1u);
      cand[w][slot] = key;
    }
  }

#pragma unroll 1
  for (int p = 0; p < 6; ++p) {
    if (m <= 64u) break;
    const int shift = (p < 5) ? (26 - 6 * p) : 0;
#pragma unroll
    for (int s = 0; s < 4; ++s) hist[w][s][lane] = 0u;
    const int nch = (int)((m + 63u) >> 6);
    for (int c = 0; c < nch; ++c) {
      const int idx = (c << 6) + lane;
      if (idx < (int)m) atomicAdd(&hist[w][sub][(cand[w][idx] >> shift) & 63u], 1u);
    }
    unsigned cnt = hist[w][0][lane] + hist[w][1][lane] + hist[w][2][lane] + hist[w][3][lane];
    unsigned incl = cnt;
#pragma unroll
    for (int off = 1; off < 64; off <<= 1) {
      unsigned t = __shfl_up(incl, off, 64);
      if (lane >= off) incl += t;
    }
    const unsigned excl = incl - cnt;
    const bool hit = (r >= excl) && (r < incl);
    const unsigned long long hm = __ballot(hit);
    const int Dp = __ffsll(hm) - 1;
    r -= __shfl(excl, Dp, 64);
    const unsigned m2 = __shfl(cnt, Dp, 64);
    if (lane == 0) apcnt[w] = 0u;
    for (int c = 0; c < nch; ++c) {
      const int idx = (c << 6) + lane;
      const bool va = idx < (int)m;
      const unsigned kk = va ? cand[w][idx] : 0u;
      if (va && (((kk >> shift) & 63u) == (unsigned)Dp)) {
        const unsigned slot = atomicAdd(&apcnt[w], 1u);
        cand[w][slot] = kk;
      }
    }
    m = m2;
  }

  unsigned selKey = 0;
  bool win = false;
  if (m > 64u) {
    selKey = cand[w][0];
    win = (lane == 0);
  } else {
    const unsigned myk = (lane < (int)m) ? cand[w][lane] : 0xFFFFFFFFu;
    unsigned cl = 0, ce = 0;
    for (int j = 0; j < (int)m; ++j) {
      const unsigned kj = cand[w][j];   // uniform addr -> LDS broadcast
      cl += (kj < myk) ? 1u : 0u;
      ce += (kj == myk) ? 1u : 0u;
    }
    selKey = myk;
    win = (lane < (int)m) && (cl <= r) && (r < cl + ce);
  }
  if (win) {
    const unsigned b = (selKey & 0x80000000u) ? (selKey & 0x7fffffffu) : ~selKey;
    med[row] = __uint_as_float(b);
  }
}

// ---------------- Kernel 2: split-k GEMM partials ----------------------------
// Tile 32o x 32b x 192k per block; 2o x 2b per thread, all-float4 LDS reads.
// Stage once (straight float4 copy, no transpose), ONE sync, 48-chunk loop.
// part[kz][b][1024] partial sums in ws; reduced by kernel 3.
#define KSP 192

__global__ __launch_bounds__(256) void gemm_partial(
    const float* __restrict__ med, const float* __restrict__ W,
    float* __restrict__ part) {
  __shared__ __align__(16) float Ws[32][196];  // stride 196: 196%32=4 ->
  __shared__ __align__(16) float Ms[32][196];  //  2-way aliasing only (free)

  const int tid = threadIdx.x;
  const int o0 = blockIdx.x * 32;      // 0..992 (o >= 1000 zero-padded)
  const int b0 = blockIdx.y * 32;      // 0..96
  const int k0 = blockIdx.z * KSP;     // 0..576

  // stage both tiles: 32 rows x 48 float4 each; 6 f4 per thread per tile
#pragma unroll
  for (int i = tid; i < 32 * 48; i += 256) {
    const int rw = i / 48, q = i % 48;
    const int o = o0 + rw;
    const float4 wv = (o < 1000)
        ? *(const float4*)&W[(size_t)o * 768 + k0 + 4 * q]
        : make_float4(0.f, 0.f, 0.f, 0.f);
    *(float4*)&Ws[rw][4 * q] = wv;
    *(float4*)&Ms[rw][4 * q] =
        *(const float4*)&med[(size_t)(b0 + rw) * 768 + k0 + 4 * q];
  }
  __syncthreads();

  const int to = tid & 15, tb = tid >> 4;
  float a00 = 0.f, a01 = 0.f, a10 = 0.f, a11 = 0.f;
#pragma unroll 4
  for (int c = 0; c < 48; ++c) {
    const float4 w0 = *(const float4*)&Ws[to][4 * c];
    const float4 w1 = *(const float4*)&Ws[to + 16][4 * c];
    const float4 m0 = *(const float4*)&Ms[tb][4 * c];
    const float4 m1 = *(const float4*)&Ms[tb + 16][4 * c];
    a00 = fmaf(w0.x, m0.x, a00); a00 = fmaf(w0.y, m0.y, a00);
    a00 = fmaf(w0.z, m0.z, a00); a00 = fmaf(w0.w, m0.w, a00);
    a10 = fmaf(w1.x, m0.x, a10); a10 = fmaf(w1.y, m0.y, a10);
    a10 = fmaf(w1.z, m0.z, a10); a10 = fmaf(w1.w, m0.w, a10);
    a01 = fmaf(w0.x, m1.x, a01); a01 = fmaf(w0.y, m1.y, a01);
    a01 = fmaf(w0.z, m1.z, a01); a01 = fmaf(w0.w, m1.w, a01);
    a11 = fmaf(w1.x, m1.x, a11); a11 = fmaf(w1.y, m1.y, a11);
    a11 = fmaf(w1.z, m1.z, a11); a11 = fmaf(w1.w, m1.w, a11);
  }

  float* p = part + (size_t)blockIdx.z * 131072;   // [128][1024] per split
  p[(size_t)(b0 + tb)      * 1024 + o0 + to]      = a00;
  p[(size_t)(b0 + tb)      * 1024 + o0 + to + 16] = a10;
  p[(size_t)(b0 + tb + 16) * 1024 + o0 + to]      = a01;
  p[(size_t)(b0 + tb + 16) * 1024 + o0 + to + 16] = a11;
}

// ---------------- Kernel 3: reduce 4 partials + bias -------------------------
__global__ __launch_bounds__(256) void reduce_bias_kernel(
    const float* __restrict__ part, const float* __restrict__ bias,
    float* __restrict__ out) {
  const int idx = blockIdx.x * 256 + threadIdx.x;   // over 128 x 1024
  const int b = idx >> 10, o = idx & 1023;
  if (o < 1000) {
    const float s = part[idx] + part[131072 + idx] +
                    part[262144 + idx] + part[393216 + idx];
    out[(size_t)b * 1000 + o] = s + bias[o];
  }
}

extern "C" void kernel_launch(void* const* d_in, const int* in_sizes, int n_in,
                              void* d_out, int out_size, void* d_ws, size_t ws_size,
                              hipStream_t stream) {
  const float* x = (const float*)d_in[0];    // [128,768,28,28]
  const float* W = (const float*)d_in[1];    // [1000,768]
  const float* b = (const float*)d_in[2];    // [1000]
  float* out = (float*)d_out;                // [128,1000]
  float* med = (float*)d_ws;                 // [128,768] f32
  float* part = med + 128 * 768;             // [4][128][1024] f32 partials

  const int rows = 128 * 768;                // 98304
  kth_select_kernel<<<rows / NWAVE, 256, 0, stream>>>(x, med);

  dim3 g2(32, 4, 4);                         // 512 blocks
  gemm_partial<<<g2, 256, 0, stream>>>(med, W, part);

  reduce_bias_kernel<<<512, 256, 0, stream>>>(part, b, out);
}